// Round 3
// baseline (176.179 us; speedup 1.0000x reference)
//
#include <hip/hip_runtime.h>

// out[b, c, w, f] = X[b, c, f*HOP + w]
// B=16, C=2, T=262144, WINDOW=1024, HOP=256, NF=1021
#define WINDOW_SZ 1024
#define HOP_SZ    256
#define NFRAMES   1021
#define T_LEN     262144

#define WROWS 16                      // output rows (w) per block
#define REGION (WROWS * NFRAMES)      // 16336 floats = 65,344 B = exactly 1021 full 64B lines
#define NPASS_LD 8                    // 1021 frames / 128 frames-per-pass
#define NVEC4 (REGION / 4)            // 4084 float4 stores per block

// clang ext-vector: accepted by __builtin_nontemporal_store (HIP_vector_type is not)
typedef float f4 __attribute__((ext_vector_type(4)));

__global__ __launch_bounds__(512)
void frame_transpose_kernel(const float* __restrict__ X,
                            float* __restrict__ out) {
    // Flat LDS image of this block's output region: lds[wl*1021 + f]
    __shared__ float lds[REGION];     // 63.8 KiB -> 2 blocks/CU (16 waves)

    // 2048 blocks. Chunked XCD swizzle: each XCD gets a contiguous 256-work
    // chunk = 4 complete bc slabs (1 MiB input each -> L2-resident).
    // Within a slab, w-tiles ordered w0 = inner*256 + outer*16 so the 4
    // blocks of a group read byte-identical input lines (frame-shifted):
    // 4x overlap becomes 1 fetch + 3 L2 hits.
    const int bid  = blockIdx.x;
    const int work = ((bid & 7) << 8) | (bid >> 3);
    const int bc    = work >> 6;          // 0..31
    const int wt    = work & 63;          // 0..63
    const int outer = wt >> 2;            // 0..15
    const int inner = wt & 3;             // 0..3
    const int w0    = inner * 256 + outer * 16;

    const int tid = threadIdx.x;
    const float* Xbc = X + (size_t)bc * T_LEN;

    // ---- phase 1: gather input, transpose into flat LDS ----
    // thread: q = w-quad (0..3), fo = frame offset (0..127); 128 frames/pass.
    // Per wave-instruction: 16 frames x 64 B = 16 full lines, 100% utilized.
    {
        const int q  = tid & 3;
        const int fo = tid >> 2;
        const int wl = 4 * q;
#pragma unroll
        for (int p = 0; p < NPASS_LD; ++p) {
            const int f = p * 128 + fo;
            if (f < NFRAMES) {
                const f4 v = *(const f4*)(Xbc + (size_t)f * HOP_SZ + w0 + wl);
                // flat layout: lds[wl*1021 + f]; stride-1021 scalar writes,
                // ~2-3-way banks (1021 % 32 = 29) -- acceptable
                lds[(wl + 0) * NFRAMES + f] = v.x;
                lds[(wl + 1) * NFRAMES + f] = v.y;
                lds[(wl + 2) * NFRAMES + f] = v.z;
                lds[(wl + 3) * NFRAMES + f] = v.w;
            }
        }
    }

    __syncthreads();

    // ---- phase 2: stream the region out as one contiguous, 64B-aligned blob ----
    // Region base byte = (bc*1024 + w0)*4084, w0 % 16 == 0 -> multiple of 64.
    // 4084 float4s, all full lines, no RMW, no tail divergence across blocks.
    {
        float* obase = out + (size_t)(bc * WINDOW_SZ + w0) * NFRAMES;
#pragma unroll
        for (int p = 0; p < 8; ++p) {
            const int idx = p * 512 + tid;
            if (idx < NVEC4) {
                const f4 t = *(const f4*)&lds[4 * idx];
                __builtin_nontemporal_store(t, (f4*)(obase + 4 * (size_t)idx));
            }
        }
    }
}

extern "C" void kernel_launch(void* const* d_in, const int* in_sizes, int n_in,
                              void* d_out, int out_size, void* d_ws, size_t ws_size,
                              hipStream_t stream) {
    const float* X = (const float*)d_in[0];
    float* out = (float*)d_out;

    dim3 block(512, 1, 1);
    dim3 grid(32 * 64, 1, 1);   // bc (32) x w-tiles of 16 rows (64), swizzled in-kernel
    frame_transpose_kernel<<<grid, block, 0, stream>>>(X, out);
}

// Round 4
// 173.103 us; speedup vs baseline: 1.0178x; 1.0178x over previous
//
#include <hip/hip_runtime.h>

// out[b, c, w, f] = X[b, c, f*HOP + w]
// B=16, C=2, T=262144, WINDOW=1024, HOP=256, NF=1021
#define WINDOW_SZ 1024
#define HOP_SZ    256
#define NFRAMES   1021
#define T_LEN     262144

#define WROWS 16                      // output rows (w) per block
#define REGION (WROWS * NFRAMES)      // 16336 floats = 65,344 B = exactly 1021 full 64B lines
#define NPASS_LD 8                    // 1021 frames / 128 frames-per-pass
#define NVEC4 (REGION / 4)            // 4084 float4 stores per block

typedef float f4 __attribute__((ext_vector_type(4)));

__global__ __launch_bounds__(512)
void frame_transpose_kernel(const float* __restrict__ X,
                            float* __restrict__ out) {
    // Flat LDS image of this block's output region: lds[wl*1021 + f]
    __shared__ float lds[REGION];     // 63.8 KiB -> 2 blocks/CU (16 waves)

    // 2048 blocks. Chunked XCD swizzle: each XCD gets a contiguous 256-work
    // chunk = 4 complete bc slabs (1 MiB input each -> L2-resident).
    // Within a slab, consecutive works vary 'inner' fastest, so the 4 blocks
    // whose input line-sets alias (w0 differing by 256) are schedule-adjacent
    // on the same XCD: 4x overlap -> 1 fetch + 3 L2 hits.
    const int bid  = blockIdx.x;
    const int work = ((bid & 7) << 8) | (bid >> 3);
    const int bc    = work >> 6;          // 0..31
    const int wt    = work & 63;          // 0..63
    const int outer = wt >> 2;            // 0..15
    const int inner = wt & 3;             // 0..3
    const int w0    = inner * 256 + outer * 16;

    const int tid = threadIdx.x;
    const float* Xbc = X + (size_t)bc * T_LEN;

    // ---- phase 1: gather input, transpose into flat LDS ----
    // thread: q = w-quad (0..3), fo = frame offset (0..127); 128 frames/pass.
    // Per wave-instruction: 16 frames x 64 B = 16 full lines, 100% utilized.
    {
        const int q  = tid & 3;
        const int fo = tid >> 2;
        const int wl = 4 * q;
#pragma unroll
        for (int p = 0; p < NPASS_LD; ++p) {
            const int f = p * 128 + fo;
            if (f < NFRAMES) {
                const f4 v = *(const f4*)(Xbc + (size_t)f * HOP_SZ + w0 + wl);
                // flat layout: lds[wl*1021 + f]; stride-1021 scalar writes,
                // bank spread {0,20,8,28}+fo over the wave -> 2-way only (free)
                lds[(wl + 0) * NFRAMES + f] = v.x;
                lds[(wl + 1) * NFRAMES + f] = v.y;
                lds[(wl + 2) * NFRAMES + f] = v.z;
                lds[(wl + 3) * NFRAMES + f] = v.w;
            }
        }
    }

    __syncthreads();

    // ---- phase 2: stream the region out as one contiguous, 64B-aligned blob ----
    // Region base byte = (bc*1024 + w0)*4084, w0 % 16 == 0 -> multiple of 64.
    // 4084 float4s, all full lines, no RMW, no tail divergence across blocks.
    // Plain stores (NOT nontemporal): L2 write-combining assembles the 16B
    // lane-stores into full 64B lines; NT bypassed L2 and broke combining.
    {
        float* obase = out + (size_t)(bc * WINDOW_SZ + w0) * NFRAMES;
#pragma unroll
        for (int p = 0; p < 8; ++p) {
            const int idx = p * 512 + tid;
            if (idx < NVEC4) {
                const f4 t = *(const f4*)&lds[4 * idx];
                *(f4*)(obase + 4 * (size_t)idx) = t;
            }
        }
    }
}

extern "C" void kernel_launch(void* const* d_in, const int* in_sizes, int n_in,
                              void* d_out, int out_size, void* d_ws, size_t ws_size,
                              hipStream_t stream) {
    const float* X = (const float*)d_in[0];
    float* out = (float*)d_out;

    dim3 block(512, 1, 1);
    dim3 grid(32 * 64, 1, 1);   // bc (32) x w-tiles of 16 rows (64), swizzled in-kernel
    frame_transpose_kernel<<<grid, block, 0, stream>>>(X, out);
}

// Round 5
// 157.422 us; speedup vs baseline: 1.1192x; 1.0996x over previous
//
#include <hip/hip_runtime.h>

// out[b, c, w, f] = X[b, c, f*HOP + w]
// B=16, C=2, T=262144, WINDOW=1024, HOP=256, NF=1021
#define WINDOW_SZ 1024
#define HOP_SZ    256
#define NFRAMES   1021
#define T_LEN     262144

#define NLINES 1024   // frames staged per block (1021 used + 3 for the k-shift)
#define WG_ROWS 16    // w-offsets per block = one 64B sub-line of every frame

typedef float f4  __attribute__((ext_vector_type(4)));
typedef float f4u __attribute__((ext_vector_type(4), aligned(4)));

// Read-once / write-once framing:
//  - block (bc, wg) reads bytes [wg*64, wg*64+64) of every 1KB frame in slab bc:
//    1024 full aligned 64B lines, each input byte read EXACTLY ONCE globally
//    (no inter-block reuse, no L2-timing dependence).
//  - it owns output rows w = 256k + 16wg + r (k=0..3, r=0..15): 4 contiguous
//    regions of 16*1021 floats = 65,344 B = exactly 1021 full aligned 64B
//    lines each -> no partial-line RMW anywhere.
//  - out[w][f] = X[256f + w] = X[256(f+k) + 16wg + r] = lds[r][f+k]: the
//    k-shift is two aligned b128 LDS reads + compile-time register shuffle.
__global__ __launch_bounds__(512)
void frame_transpose_kernel(const float* __restrict__ X,
                            float* __restrict__ out) {
    __shared__ float lds[WG_ROWS * NLINES];   // 64 KiB -> 2 blocks/CU, 512 blocks = 2/CU exactly

    const int bid = blockIdx.x;
    const int bc  = bid >> 4;     // 0..31
    const int wg  = bid & 15;     // 0..15
    const int t   = threadIdx.x;

    const float* Xbc = X + (size_t)bc * T_LEN + wg * 16;

    // ---- phase 1: 8 x f4 loads/thread, every line fetched once ----
    // wave instr = 16 distinct full 64B lines (4 lanes per line), coalesced.
#pragma unroll
    for (int p = 0; p < 8; ++p) {
        const int idx  = p * 512 + t;     // 0..4095
        const int line = idx >> 2;        // frame 0..1023
        const int sub  = idx & 3;         // f4 within the 64B line
        const f4 v = *(const f4*)(Xbc + line * HOP_SZ + 4 * sub);
        // lds[r][line], r = 4*sub..4*sub+3; 4-way bank alias on a tiny phase -- fine
        lds[(4 * sub + 0) * NLINES + line] = v.x;
        lds[(4 * sub + 1) * NLINES + line] = v.y;
        lds[(4 * sub + 2) * NLINES + line] = v.z;
        lds[(4 * sub + 3) * NLINES + line] = v.w;
    }

    __syncthreads();

    // ---- phase 2: 4 output regions, all full-line writes ----
#pragma unroll
    for (int k = 0; k < 4; ++k) {
        float* obase = out + (size_t)(bc * WINDOW_SZ + 256 * k + 16 * wg) * NFRAMES;
#pragma unroll
        for (int p = 0; p < 8; ++p) {
            const int slot = p * 512 + t;   // 0..4095 = 16 rows x 256 slots
            const int row  = slot >> 8;     // r = 0..15 (wave-uniform)
            const int pos  = slot & 255;    // f4 slot in the row
            const float* lrow = &lds[row * NLINES + 4 * pos];
            if (pos < 255) {
                // aligned b128 reads (consecutive lanes -> consecutive quads, conflict-free)
                const f4 q0 = *(const f4*)(lrow);
                const f4 q1 = *(const f4*)(lrow + 4);
                f4 o;
                if      (k == 0) o = q0;
                else if (k == 1) o = f4{q0.y, q0.z, q0.w, q1.x};
                else if (k == 2) o = f4{q0.z, q0.w, q1.x, q1.y};
                else             o = f4{q0.w, q1.x, q1.y, q1.z};
                // rows are 1021-strided -> only 4B-aligned: unaligned-capable vec4 store
                *(f4u*)(obase + (size_t)row * NFRAMES + 4 * pos) = o;
            } else {
                // row tail: f = 1020 (1021 = 255*4 + 1)
                obase[(size_t)row * NFRAMES + 1020] = lrow[k];
            }
        }
    }
}

extern "C" void kernel_launch(void* const* d_in, const int* in_sizes, int n_in,
                              void* d_out, int out_size, void* d_ws, size_t ws_size,
                              hipStream_t stream) {
    const float* X = (const float*)d_in[0];
    float* out = (float*)d_out;

    dim3 block(512, 1, 1);
    dim3 grid(32 * 16, 1, 1);   // bc (32) x wg (16): 512 blocks, 2 per CU
    frame_transpose_kernel<<<grid, block, 0, stream>>>(X, out);
}